// Round 8
// baseline (2429.810 us; speedup 1.0000x reference)
//
#include <hip/hip_runtime.h>
#include <hip/hip_fp16.h>
#include <math.h>

#define B_ 16
#define L_ 2048
#define D_ 256
#define N_ 64
#define NBLK_ 6
#define LC_ 128
#define NC_ 16
#define NBLOCKS 512

typedef _Float16 half8 __attribute__((ext_vector_type(8)));
typedef float f32x4 __attribute__((ext_vector_type(4)));

__device__ __forceinline__ unsigned short f2h(float f) {
  _Float16 h = (_Float16)f;
  return *(unsigned short*)&h;
}
__device__ __forceinline__ float h2f(unsigned short u) {
  _Float16 h = *(_Float16*)&u;
  return (float)h;
}

// ---- grid barrier: all NBLOCKS co-resident (2 blocks/CU by launch_bounds) ----
__device__ __forceinline__ void gbar(int* cnt, int* epoch, int target) {
  __syncthreads();
  if (threadIdx.x == 0) {
    __threadfence();
    int prev = __hip_atomic_fetch_add(cnt, 1, __ATOMIC_ACQ_REL, __HIP_MEMORY_SCOPE_AGENT);
    if (prev == NBLOCKS - 1) {
      __hip_atomic_store(cnt, 0, __ATOMIC_RELAXED, __HIP_MEMORY_SCOPE_AGENT);
      __hip_atomic_fetch_add(epoch, 1, __ATOMIC_ACQ_REL, __HIP_MEMORY_SCOPE_AGENT);
    } else {
      while (__hip_atomic_load(epoch, __ATOMIC_ACQUIRE, __HIP_MEMORY_SCOPE_AGENT) < target) {
        __builtin_amdgcn_s_sleep(2);
      }
    }
    __threadfence();
  }
  __syncthreads();
}

// ---- shared gemm phase: out[32768x256] over K=256, 128x128 tiles, 512 thr ----
// a_kmajor: A read from GT (k-major); else A m-major ([m][k]).
__device__ __forceinline__ void gemm_phase(
    unsigned char* LDSRAW, int bid, int tid,
    const unsigned short* __restrict__ A, const unsigned short* __restrict__ Wt,
    const float* __restrict__ bias, const unsigned short* __restrict__ res,
    unsigned short* __restrict__ hout, unsigned short* __restrict__ ut_next,
    bool a_kmajor, bool relu) {
  unsigned short* As = (unsigned short*)LDSRAW;            // [128][72]
  unsigned short* Bs = As + 9216;                          // [128][72]
  int bc = bid >> 1;
  int m0 = bc << 7, n0 = (bid & 1) << 7;
  int lane = tid & 63, w = tid >> 6;
  int wm = (w & 1) << 6, wn = (w >> 1) << 5;
  int cn = lane & 15, rq = lane >> 4;
  f32x4 acc[4][2];
#pragma unroll
  for (int mf = 0; mf < 4; ++mf)
#pragma unroll
    for (int nf = 0; nf < 2; ++nf) acc[mf][nf] = (f32x4){0.f, 0.f, 0.f, 0.f};

  // staging indices
  int drA = tid >> 3, sgA = (tid & 7) << 4;   // k-major A: k-row, 16 tau
  int rA = tid >> 2, cA = (tid & 3) << 4;     // m-major A and B: row, 16 k
  uint4 ga[2], gb[2];
  if (a_kmajor) {
    const uint4* p = (const uint4*)(A + ((size_t)(drA * 256 + bc)) * 128 + sgA);
    ga[0] = p[0]; ga[1] = p[1];
  } else {
    const uint4* p = (const uint4*)(A + (size_t)(m0 + rA) * 256 + cA);
    ga[0] = p[0]; ga[1] = p[1];
  }
  {
    const uint4* p = (const uint4*)(Wt + (size_t)(n0 + rA) * 256 + cA);
    gb[0] = p[0]; gb[1] = p[1];
  }
  for (int kb = 0; kb < 4; ++kb) {
    __syncthreads();
    if (a_kmajor) {
      const unsigned short* pv = (const unsigned short*)ga;
#pragma unroll
      for (int i = 0; i < 16; ++i) As[(sgA + i) * 72 + drA] = pv[i];
    } else {
      *(uint4*)&As[rA * 72 + cA] = ga[0];
      *(uint4*)&As[rA * 72 + cA + 8] = ga[1];
    }
    *(uint4*)&Bs[rA * 72 + cA] = gb[0];
    *(uint4*)&Bs[rA * 72 + cA + 8] = gb[1];
    __syncthreads();
    if (kb < 3) {
      int k0 = (kb + 1) << 6;
      if (a_kmajor) {
        const uint4* p = (const uint4*)(A + ((size_t)((k0 + drA) * 256 + bc)) * 128 + sgA);
        ga[0] = p[0]; ga[1] = p[1];
      } else {
        const uint4* p = (const uint4*)(A + (size_t)(m0 + rA) * 256 + k0 + cA);
        ga[0] = p[0]; ga[1] = p[1];
      }
      const uint4* p = (const uint4*)(Wt + (size_t)(n0 + rA) * 256 + k0 + cA);
      gb[0] = p[0]; gb[1] = p[1];
    }
#pragma unroll
    for (int kw = 0; kw < 2; ++kw) {
      int ko = (kw << 5) + (rq << 3);
      half8 af[4], bf[2];
#pragma unroll
      for (int mf = 0; mf < 4; ++mf)
        af[mf] = *(const half8*)&As[(wm + (mf << 4) + cn) * 72 + ko];
#pragma unroll
      for (int nf = 0; nf < 2; ++nf)
        bf[nf] = *(const half8*)&Bs[(wn + (nf << 4) + cn) * 72 + ko];
#pragma unroll
      for (int mf = 0; mf < 4; ++mf)
#pragma unroll
        for (int nf = 0; nf < 2; ++nf)
          acc[mf][nf] = __builtin_amdgcn_mfma_f32_16x16x32_f16(af[mf], bf[nf], acc[mf][nf], 0, 0, 0);
    }
  }
  __syncthreads();
  unsigned short* epi = (unsigned short*)LDSRAW;   // [128][136]
#pragma unroll
  for (int nf = 0; nf < 2; ++nf) {
    int nl = wn + (nf << 4) + cn;
    float bv2 = bias[n0 + nl];
#pragma unroll
    for (int mf = 0; mf < 4; ++mf)
#pragma unroll
      for (int r = 0; r < 4; ++r) {
        int ml = wm + (mf << 4) + (rq << 2) + r;
        float v = acc[mf][nf][r] + bv2;
        if (res) v += h2f(res[(size_t)(m0 + ml) * 256 + n0 + nl]);
        if (relu) v = fmaxf(v, 0.f);
        epi[ml * 136 + nl] = f2h(v);
      }
  }
  __syncthreads();
  {
    int mr = tid >> 2, hf = (tid & 3) << 5;
    unsigned short* dst = hout + (size_t)(m0 + mr) * 256 + n0 + hf;
    const unsigned short* srow = epi + mr * 136 + hf;
#pragma unroll
    for (int k = 0; k < 4; ++k) *(uint4*)(dst + k * 8) = *(const uint4*)(srow + k * 8);
  }
  if (ut_next) {
    int nl = tid >> 2, sg2 = (tid & 3) << 5;
    unsigned short* dst = ut_next + ((size_t)(n0 + nl) * 256 + bc) * 128 + sg2;
#pragma unroll
    for (int k = 0; k < 4; ++k) {
      unsigned short v8[8];
#pragma unroll
      for (int e = 0; e < 8; ++e) v8[e] = epi[(sg2 + k * 8 + e) * 136 + nl];
      *(uint4*)(dst + k * 8) = *(uint4*)v8;
    }
  }
}

// ---------------- the whole network in one persistent kernel ----------------
__global__ __launch_bounds__(512, 4) void fused_net(
    const float* __restrict__ x, const float* __restrict__ wemb,
    const float* __restrict__ bemb,
    const float* __restrict__ log_dt, const float* __restrict__ logAre,
    const float* __restrict__ Aim, const float* __restrict__ Cre,
    const float* __restrict__ Cim, const float* __restrict__ dskip,
    const float* __restrict__ Wout, const float* __restrict__ bout,
    const float* __restrict__ gamma_, const float* __restrict__ beta_,
    const float* __restrict__ fb1, const float* __restrict__ fb2,
    const float* __restrict__ fcW, const float* __restrict__ fcb,
    const float* __restrict__ fW1, const float* __restrict__ fW2,
    float* __restrict__ WB, float* __restrict__ C2B, float* __restrict__ WLB,
    unsigned short* __restrict__ H, unsigned short* __restrict__ R,
    unsigned short* __restrict__ UT, unsigned short* __restrict__ GT,
    unsigned short* __restrict__ WT, float* __restrict__ part,
    float* __restrict__ outp, int* cnt, int* epoch) {
  __shared__ __align__(16) unsigned char LDSRAW[73728];
  int bid = blockIdx.x;
  int tid = threadIdx.x;
  int ep = 0;

  // ================= P0: precompute + wprep + embed =================
  if (bid < 192) {
    int idx = bid * 512 + tid;   // 192*512 = 98304 = NBLK*D*N exactly
    int blk = idx >> 14;
    int rem = idx & 16383;
    int d = rem >> 6;
    int n = rem & 63;
    float dt   = expf(log_dt[blk * D_ + d]);
    float are  = -expf(logAre[idx]);
    float aim  = Aim[idx];
    float dtar = dt * are, dtai = dt * aim;
    float er = expf(dtar);
    float wr = er * cosf(dtai);
    float wi = er * sinf(dtai);
    float inv = 1.0f / (are * are + aim * aim);
    float wm1r = wr - 1.0f;
    float br = (wm1r * are + wi * aim) * inv;
    float bi2 = (wi * are - wm1r * aim) * inv;
    float crv = Cre[idx], civ = Cim[idx];
    float c2r = 2.0f * (crv * br - civ * bi2);
    float c2i = 2.0f * (crv * bi2 + civ * br);
    float eL = expf((float)LC_ * dtar);
    float angL = (float)LC_ * dtai;
    float* wb = WB + (size_t)((blk << 8) + d) * 128;
    wb[n] = wr; wb[64 + n] = wi;
    float* cb = C2B + (size_t)((blk << 8) + d) * 128;
    cb[n] = c2r; cb[64 + n] = c2i;
    WLB[2 * idx] = eL * cosf(angL); WLB[2 * idx + 1] = eL * sinf(angL);
  } else if (bid < 320) {
    // wprep: task = bid-192 in 0..127 : wv(8) x tk(4) x tn(4)
    float (*tile)[65] = (float (*)[65])LDSRAW;
    int b2 = bid - 192;
    int wv = b2 >> 4, tk = (b2 >> 2) & 3, tn = b2 & 3;
    const float* src = (wv < 6) ? (Wout + (size_t)wv * 65536) : (wv == 6 ? fW1 : fW2);
    int r = tid >> 3, c = (tid & 7) << 3;
    float4 v0 = *(const float4*)(src + (size_t)(tk * 64 + r) * 256 + tn * 64 + c);
    float4 v1 = *(const float4*)(src + (size_t)(tk * 64 + r) * 256 + tn * 64 + c + 4);
    tile[r][c] = v0.x; tile[r][c + 1] = v0.y; tile[r][c + 2] = v0.z; tile[r][c + 3] = v0.w;
    tile[r][c + 4] = v1.x; tile[r][c + 5] = v1.y; tile[r][c + 6] = v1.z; tile[r][c + 7] = v1.w;
    __syncthreads();
    int n = tid >> 3, cc = (tid & 7) << 3;
    unsigned short o8[8];
#pragma unroll
    for (int e = 0; e < 8; ++e) o8[e] = f2h(tile[cc + e][n]);
    *(uint4*)(WT + (size_t)wv * 65536 + (size_t)(tn * 64 + n) * 256 + tk * 64 + cc) = *(uint4*)o8;
  }
  __syncthreads();
  {
    // embed: every block does one (bc, tau-half): bc = bid>>1, th = bid&1
    unsigned short* lds = (unsigned short*)LDSRAW;   // [256][72]
    int bc = bid >> 1, th = bid & 1;
    int b = bc >> 4, ch = bc & 15;
    int dl = (tid & 63) << 2;
    int tg = tid >> 6;
    float w4[4], b4[4];
#pragma unroll
    for (int i = 0; i < 4; ++i) { w4[i] = wemb[dl + i]; b4[i] = bemb[dl + i]; }
    for (int tt = 0; tt < 64; tt += 8) {
      int tau = tt + tg;
      int l = ch * 128 + th * 64 + tau;
      float xv = x[b * L_ + l];
      ushort4 hv;
      hv.x = f2h(fmaf(xv, w4[0], b4[0]));
      hv.y = f2h(fmaf(xv, w4[1], b4[1]));
      hv.z = f2h(fmaf(xv, w4[2], b4[2]));
      hv.w = f2h(fmaf(xv, w4[3], b4[3]));
      lds[(dl + 0) * 72 + tau] = hv.x;
      lds[(dl + 1) * 72 + tau] = hv.y;
      lds[(dl + 2) * 72 + tau] = hv.z;
      lds[(dl + 3) * 72 + tau] = hv.w;
      *(ushort4*)(H + ((size_t)(b * L_ + l)) * D_ + dl) = hv;
    }
    __syncthreads();
    int d = tid >> 1, sg = (tid & 1) << 5;
    unsigned short* dst = UT + ((size_t)d * 256 + bc) * 128 + th * 64 + sg;
    const unsigned short* srow = lds + d * 72 + sg;
    *(uint4*)(dst + 0)  = *(const uint4*)(srow + 0);
    *(uint4*)(dst + 8)  = *(const uint4*)(srow + 8);
    *(uint4*)(dst + 16) = *(const uint4*)(srow + 16);
    *(uint4*)(dst + 24) = *(const uint4*)(srow + 24);
  }
  gbar(cnt, epoch, ++ep);

  // ================= 6 layers: scan -> bar -> gemm -> bar =================
#pragma unroll 1
  for (int blk = 0; blk < NBLK_; ++blk) {
    {
      // ---- scan (round-5 verified body): block = (d, batch-half) ----
      unsigned short* SLl = (unsigned short*)LDSRAW;            // [128][136]
      unsigned short* Bm  = SLl + 17408;                        // [128][136]
      float* wc = (float*)(LDSRAW + 69632);                     // [256]
      float* Kt = wc + 256;                                     // [128]
      float* Pb = Kt + 128;                                     // [128]
      float* Sb = Pb + 128;                                     // [128]
      int d = bid >> 1;
      int hm = (bid & 1) << 7;
      int lane = tid & 63, w = tid >> 6;
      int wm = w << 4;
      int cn = lane & 15, rq = lane >> 4;
      int ko = rq << 3;
      const unsigned short* Au = UT + ((size_t)d * 256 + hm) * 128;
      half8 afr[4];
#pragma unroll
      for (int kc2 = 0; kc2 < 4; ++kc2)
        afr[kc2] = *(const half8*)(Au + (size_t)(wm + cn) * 128 + (kc2 << 5) + ko);
      if (tid < 128) wc[tid] = WB[(size_t)((blk << 8) + d) * 128 + tid];
      else if (tid < 256) wc[tid] = C2B[(size_t)((blk << 8) + d) * 128 + (tid - 128)];
      __syncthreads();
      int n = tid & 63;
      float gd = gamma_[blk * D_ + d], bd = beta_[blk * D_ + d], dsk = dskip[blk * D_ + d];
      float wr = wc[n], wi = wc[64 + n];
      float c2r = wc[128 + n], c2i = wc[192 + n];
      float pr0, pi0;
      int j0 = w << 4;
      {
        float pr = 1.f, pi = 0.f, br = wr, bi = wi;
        int e = j0;
        while (e) {
          if (e & 1) { float tt = pr * br - pi * bi; pi = pr * bi + pi * br; pr = tt; }
          float t2 = br * br - bi * bi; bi = 2.f * br * bi; br = t2;
          e >>= 1;
        }
        pr0 = pr; pi0 = pi;
#pragma unroll 4
        for (int k2 = 0; k2 < 16; ++k2) {
          int j = j0 + k2;
          Bm[n * 136 + (127 - j)]        = f2h(gd * pr);
          Bm[(64 + n) * 136 + (127 - j)] = f2h(-gd * pi);
          float qr = pr * wr - pi * wi, qi = pr * wi + pi * wr;
          float kc = c2r * pr - c2i * pi;
#pragma unroll
          for (int off = 1; off < 64; off <<= 1) kc += __shfl_xor(kc, off);
          if (n == 0) Kt[j] = kc + (j == 0 ? dsk : 0.f);
          pr = qr; pi = qi;
        }
      }
      if (tid < 64) {
        const float* wlp = WLB + (((size_t)((blk << 8) + d)) * 64 + tid) * 2;
        float wlr = wlp[0], wli = wlp[1];
        float nr = wlr - 1.f, ni = wli;
        float dr2 = wc[tid] - 1.f, di = wc[64 + tid];
        float iv = 1.f / (dr2 * dr2 + di * di);
        Sb[tid]      = bd * ((nr * dr2 + ni * di) * iv);
        Sb[64 + tid] = bd * (-((ni * dr2 - nr * di) * iv));
      }
      __syncthreads();
      {
        f32x4 acc[8];
#pragma unroll
        for (int a = 0; a < 8; ++a) acc[a] = (f32x4){0.f, 0.f, 0.f, 0.f};
        __builtin_amdgcn_s_setprio(1);
#pragma unroll
        for (int kc = 0; kc < 4; ++kc) {
#pragma unroll
          for (int nf = 0; nf < 8; ++nf) {
            half8 bf = *(const half8*)((const _Float16*)Bm + ((nf << 4) + cn) * 136 + (kc << 5) + ko);
            acc[nf] = __builtin_amdgcn_mfma_f32_16x16x32_f16(afr[kc], bf, acc[nf], 0, 0, 0);
          }
        }
        __builtin_amdgcn_s_setprio(0);
#pragma unroll
        for (int nf = 0; nf < 8; ++nf) {
          int nl = (nf << 4) + cn;
          float sb = Sb[nl];
#pragma unroll
          for (int rr = 0; rr < 4; ++rr) {
            int row = wm + (rq << 2) + rr;
            SLl[row * 136 + nl] = f2h(acc[nf][rr] + sb);
          }
        }
      }
      __syncthreads();
      {
        float pr = pr0, pi = pi0;
#pragma unroll 4
        for (int k2 = 0; k2 < 16; ++k2) {
          int j = j0 + k2;
          float qr = pr * wr - pi * wi, qi = pr * wi + pi * wr;
          Bm[j * 136 + n]      = f2h(c2r * qr - c2i * qi);
          Bm[j * 136 + 64 + n] = f2h(c2r * qi + c2i * qr);
          pr = qr; pi = qi;
        }
      }
      if (tid < 128) {
        float ps = 0.f;
        for (int t2 = 0; t2 <= tid; ++t2) ps += Kt[t2];
        Pb[tid] = bd * ps;
      }
      {
        int b = tid >> 6, nn = tid & 63;
        const float* wlp = WLB + (((size_t)((blk << 8) + d)) * 64 + nn) * 2;
        float wlr = wlp[0], wli = wlp[1];
        float Sr = 0.f, Sj = 0.f;
        int row0 = b << 4;
        float tr2 = h2f(SLl[row0 * 136 + nn]);
        float tj2 = h2f(SLl[row0 * 136 + 64 + nn]);
        for (int c = 0; c < NC_; ++c) {
          int row = row0 + c;
          float ntr = 0.f, ntj = 0.f;
          if (c < NC_ - 1) {
            ntr = h2f(SLl[(row + 1) * 136 + nn]);
            ntj = h2f(SLl[(row + 1) * 136 + 64 + nn]);
          }
          SLl[row * 136 + nn]      = f2h(Sr);
          SLl[row * 136 + 64 + nn] = f2h(Sj);
          float nSr = fmaf(wlr, Sr, fmaf(wli, Sj, tr2));
          Sj = fmaf(-wli, Sr, fmaf(wlr, Sj, tj2));
          Sr = nSr;
          tr2 = ntr; tj2 = ntj;
        }
      }
      __syncthreads();
      f32x4 acc3[8];
#pragma unroll
      for (int a = 0; a < 8; ++a) acc3[a] = (f32x4){0.f, 0.f, 0.f, 0.f};
      __builtin_amdgcn_s_setprio(1);
#pragma unroll
      for (int kc2 = 0; kc2 < 4; ++kc2) {
        int kc = kc2 << 5;
        half8 af = *(const half8*)((const _Float16*)SLl + (wm + cn) * 136 + kc + ko);
#pragma unroll
        for (int nf = 0; nf < 8; ++nf) {
          half8 bf = *(const half8*)((const _Float16*)Bm + ((nf << 4) + cn) * 136 + kc + ko);
          acc3[nf] = __builtin_amdgcn_mfma_f32_16x16x32_f16(af, bf, acc3[nf], 0, 0, 0);
        }
      }
      __builtin_amdgcn_s_setprio(0);
      __syncthreads();
      {
        int chunk = tid & 15, rg = tid >> 4;
#pragma unroll
        for (int it = 0; it < 4; ++it) {
          int trow = (it << 5) + rg;
          int tau0 = chunk << 3;
          unsigned short v[8];
#pragma unroll
          for (int i = 0; i < 8; ++i) {
            int tau = tau0 + i;
            v[i] = (tau <= trow) ? f2h(gd * Kt[trow - tau]) : (unsigned short)0;
          }
          *(uint4*)(Bm + (size_t)trow * 136 + tau0) = *(uint4*)v;
        }
      }
      __syncthreads();
      {
        __builtin_amdgcn_s_setprio(1);
#pragma unroll
        for (int kc2 = 0; kc2 < 4; ++kc2) {
#pragma unroll
          for (int nf = 0; nf < 8; ++nf) {
            half8 bf = *(const half8*)((const _Float16*)Bm + ((nf << 4) + cn) * 136 + (kc2 << 5) + ko);
            acc3[nf] = __builtin_amdgcn_mfma_f32_16x16x32_f16(afr[kc2], bf, acc3[nf], 0, 0, 0);
          }
        }
        __builtin_amdgcn_s_setprio(0);
#pragma unroll
        for (int nf = 0; nf < 8; ++nf) {
          int nl = (nf << 4) + cn;
          float pb2 = Pb[nl];
#pragma unroll
          for (int rr = 0; rr < 4; ++rr) {
            int ml = wm + (rq << 2) + rr;
            float xx = acc3[nf][rr] + pb2;
            float x3 = xx * xx * xx;
            float inner = 0.7978845608028654f * fmaf(0.044715f, x3, xx);
            float e = __expf(-2.f * fabsf(inner));
            float th = (1.f - e) / (1.f + e);
            th = copysignf(th, inner);
            SLl[ml * 136 + nl] = f2h(0.5f * xx * (1.f + th));
          }
        }
        __syncthreads();
        int mr = tid >> 2, hf = (tid & 3) << 5;
        size_t gb2 = ((size_t)d * 256 + hm + mr) * 128 + hf;
#pragma unroll
        for (int k = 0; k < 4; ++k)
          *(uint4*)(GT + gb2 + k * 8) = *(const uint4*)&SLl[mr * 136 + hf + k * 8];
      }
    }
    gbar(cnt, epoch, ++ep);

    // ---- projection gemm ----
    {
      const unsigned short* hin = (blk == 4) ? R : H;
      unsigned short* hout = (blk == 3) ? R : H;
      gemm_phase(LDSRAW, bid, tid, GT, WT + (size_t)blk * 65536, bout + blk * D_,
                 hin, hout, (blk < 5) ? UT : nullptr, true, false);
    }
    gbar(cnt, epoch, ++ep);
  }

  // ================= FFN (Gbf aliases GT) =================
  gemm_phase(LDSRAW, bid, tid, H, WT + (size_t)6 * 65536, fb1, nullptr, GT, nullptr, false, true);
  gbar(cnt, epoch, ++ep);
  gemm_phase(LDSRAW, bid, tid, GT, WT + (size_t)7 * 65536, fb2, R, H, nullptr, false, true);
  gbar(cnt, epoch, ++ep);

  // ================= head =================
  if (bid < 256) {
    float* hs = (float*)LDSRAW;   // [2][256]
    int b = bid >> 4, ls = bid & 15;
    int d = tid & 255, hh = tid >> 8;
    const unsigned short* p = H + ((size_t)(b * L_ + ls * 128 + hh * 64)) * D_ + d;
    float sum = 0.f;
    for (int l = 0; l < 64; ++l) sum += h2f(p[(size_t)l * D_]);
    hs[hh * 256 + d] = sum;
    __syncthreads();
    if (tid < 256) part[(b * 16 + ls) * D_ + tid] = hs[tid] + hs[256 + tid];
  }
  gbar(cnt, epoch, ++ep);
  if (bid < 16) {
    float* mv = (float*)LDSRAW;
    int b = bid;
    if (tid < 256) {
      float s = 0.f;
      for (int i = 0; i < 16; ++i) s += part[(b * 16 + i) * D_ + tid];
      mv[tid] = s * (1.0f / (float)L_);
    }
    __syncthreads();
    if (tid < 2) {
      float accv = fcb[tid];
      for (int k = 0; k < D_; ++k) accv = fmaf(mv[k], fcW[k * 2 + tid], accv);
      outp[b * 2 + tid] = accv;
    }
  }
}

extern "C" void kernel_launch(void* const* d_in, const int* in_sizes, int n_in,
                              void* d_out, int out_size, void* d_ws, size_t ws_size,
                              hipStream_t stream) {
  const float* x      = (const float*)d_in[0];
  const float* W_emb  = (const float*)d_in[1];
  const float* b_emb  = (const float*)d_in[2];
  const float* log_dt = (const float*)d_in[3];
  const float* logAre = (const float*)d_in[4];
  const float* Aim    = (const float*)d_in[5];
  const float* Cre    = (const float*)d_in[6];
  const float* Cim    = (const float*)d_in[7];
  const float* Dskip  = (const float*)d_in[8];
  const float* Wout   = (const float*)d_in[9];
  const float* bout   = (const float*)d_in[10];
  const float* gamma_ = (const float*)d_in[11];
  const float* beta_  = (const float*)d_in[12];
  const float* fW1    = (const float*)d_in[13];
  const float* fb1    = (const float*)d_in[14];
  const float* fW2    = (const float*)d_in[15];
  const float* fb2    = (const float*)d_in[16];
  const float* fcW    = (const float*)d_in[17];
  const float* fcb    = (const float*)d_in[18];
  float* outp = (float*)d_out;

  const size_t HSZ = (size_t)B_ * L_ * D_;   // 8388608
  float* WB     = (float*)d_ws;                          // 196608 f
  float* C2B    = WB + (size_t)NBLK_ * D_ * 128;         // 196608 f
  float* WLB    = C2B + (size_t)NBLK_ * D_ * 128;        // 196608 f
  unsigned short* H   = (unsigned short*)(WLB + (size_t)NBLK_ * D_ * N_ * 2);
  unsigned short* R   = H + HSZ;
  unsigned short* UT  = R + HSZ;
  unsigned short* GT  = UT + HSZ;
  unsigned short* WT  = GT + HSZ;                        // 524288 us
  float* part = (float*)(WT + (size_t)8 * 65536);        // 65536 f
  int* ctrl = (int*)(part + 65536);                      // 2 ints: cnt, epoch

  hipMemsetAsync(ctrl, 0, 2 * sizeof(int), stream);
  fused_net<<<NBLOCKS, 512, 0, stream>>>(
      x, W_emb, b_emb, log_dt, logAre, Aim, Cre, Cim, Dskip,
      Wout, bout, gamma_, beta_, fb1, fb2, fcW, fcb, fW1, fW2,
      WB, C2B, WLB, H, R, UT, GT, WT, part, outp, ctrl, ctrl + 1);
}

// Round 9
// 1811.279 us; speedup vs baseline: 1.3415x; 1.3415x over previous
//
#include <hip/hip_runtime.h>
#include <hip/hip_fp16.h>
#include <math.h>

#define B_ 16
#define L_ 2048
#define D_ 256
#define N_ 64
#define NBLK_ 6
#define LC_ 128
#define NC_ 16
#define NBLOCKS 512

typedef _Float16 half8 __attribute__((ext_vector_type(8)));
typedef float f32x4 __attribute__((ext_vector_type(4)));

__device__ __forceinline__ unsigned short f2h(float f) {
  _Float16 h = (_Float16)f;
  return *(unsigned short*)&h;
}
__device__ __forceinline__ float h2f(unsigned short u) {
  _Float16 h = *(_Float16*)&u;
  return (float)h;
}

// ---- grid barrier v2: monotonic arrival count; RELAXED-RMW polls (L3, no
// cache invalidate); exactly ONE acquire (L1/L2 inv) per block per barrier ----
__device__ __forceinline__ void gbar(int* cnt, int target) {
  __syncthreads();
  if (threadIdx.x == 0) {
    __threadfence();   // release: writeback dirty L2 so other XCDs can see it
    int prev = __hip_atomic_fetch_add(cnt, 1, __ATOMIC_RELEASE,
                                      __HIP_MEMORY_SCOPE_AGENT);
    if (prev + 1 < target) {
      // relaxed RMW executes at coherence point: fresh value, no invalidates
      while (__hip_atomic_fetch_add(cnt, 0, __ATOMIC_RELAXED,
                                    __HIP_MEMORY_SCOPE_AGENT) < target)
        __builtin_amdgcn_s_sleep(32);
    }
    // single acquire: invalidate local L1/L2 once so we see remote writes
    (void)__hip_atomic_load(cnt, __ATOMIC_ACQUIRE, __HIP_MEMORY_SCOPE_AGENT);
  }
  __syncthreads();
}

// ---- shared gemm phase: out[32768x256] over K=256, 128x128 tiles, 512 thr ----
__device__ __forceinline__ void gemm_phase(
    unsigned char* LDSRAW, int bid, int tid,
    const unsigned short* __restrict__ A, const unsigned short* __restrict__ Wt,
    const float* __restrict__ bias, const unsigned short* __restrict__ res,
    unsigned short* __restrict__ hout, unsigned short* __restrict__ ut_next,
    bool a_kmajor, bool relu) {
  unsigned short* As = (unsigned short*)LDSRAW;            // [128][72]
  unsigned short* Bs = As + 9216;                          // [128][72]
  int bc = bid >> 1;
  int m0 = bc << 7, n0 = (bid & 1) << 7;
  int lane = tid & 63, w = tid >> 6;
  int wm = (w & 1) << 6, wn = (w >> 1) << 5;
  int cn = lane & 15, rq = lane >> 4;
  f32x4 acc[4][2];
#pragma unroll
  for (int mf = 0; mf < 4; ++mf)
#pragma unroll
    for (int nf = 0; nf < 2; ++nf) acc[mf][nf] = (f32x4){0.f, 0.f, 0.f, 0.f};

  int drA = tid >> 3, sgA = (tid & 7) << 4;   // k-major A: k-row, 16 tau
  int rA = tid >> 2, cA = (tid & 3) << 4;     // m-major A and B: row, 16 k
  uint4 ga[2], gb[2];
  if (a_kmajor) {
    const uint4* p = (const uint4*)(A + ((size_t)(drA * 256 + bc)) * 128 + sgA);
    ga[0] = p[0]; ga[1] = p[1];
  } else {
    const uint4* p = (const uint4*)(A + (size_t)(m0 + rA) * 256 + cA);
    ga[0] = p[0]; ga[1] = p[1];
  }
  {
    const uint4* p = (const uint4*)(Wt + (size_t)(n0 + rA) * 256 + cA);
    gb[0] = p[0]; gb[1] = p[1];
  }
  for (int kb = 0; kb < 4; ++kb) {
    __syncthreads();
    if (a_kmajor) {
      const unsigned short* pv = (const unsigned short*)ga;
#pragma unroll
      for (int i = 0; i < 16; ++i) As[(sgA + i) * 72 + drA] = pv[i];
    } else {
      *(uint4*)&As[rA * 72 + cA] = ga[0];
      *(uint4*)&As[rA * 72 + cA + 8] = ga[1];
    }
    *(uint4*)&Bs[rA * 72 + cA] = gb[0];
    *(uint4*)&Bs[rA * 72 + cA + 8] = gb[1];
    __syncthreads();
    if (kb < 3) {
      int k0 = (kb + 1) << 6;
      if (a_kmajor) {
        const uint4* p = (const uint4*)(A + ((size_t)((k0 + drA) * 256 + bc)) * 128 + sgA);
        ga[0] = p[0]; ga[1] = p[1];
      } else {
        const uint4* p = (const uint4*)(A + (size_t)(m0 + rA) * 256 + k0 + cA);
        ga[0] = p[0]; ga[1] = p[1];
      }
      const uint4* p = (const uint4*)(Wt + (size_t)(n0 + rA) * 256 + k0 + cA);
      gb[0] = p[0]; gb[1] = p[1];
    }
#pragma unroll
    for (int kw = 0; kw < 2; ++kw) {
      int ko = (kw << 5) + (rq << 3);
      half8 af[4], bf[2];
#pragma unroll
      for (int mf = 0; mf < 4; ++mf)
        af[mf] = *(const half8*)&As[(wm + (mf << 4) + cn) * 72 + ko];
#pragma unroll
      for (int nf = 0; nf < 2; ++nf)
        bf[nf] = *(const half8*)&Bs[(wn + (nf << 4) + cn) * 72 + ko];
#pragma unroll
      for (int mf = 0; mf < 4; ++mf)
#pragma unroll
        for (int nf = 0; nf < 2; ++nf)
          acc[mf][nf] = __builtin_amdgcn_mfma_f32_16x16x32_f16(af[mf], bf[nf], acc[mf][nf], 0, 0, 0);
    }
  }
  __syncthreads();
  unsigned short* epi = (unsigned short*)LDSRAW;   // [128][136]
#pragma unroll
  for (int nf = 0; nf < 2; ++nf) {
    int nl = wn + (nf << 4) + cn;
    float bv2 = bias[n0 + nl];
#pragma unroll
    for (int mf = 0; mf < 4; ++mf)
#pragma unroll
      for (int r = 0; r < 4; ++r) {
        int ml = wm + (mf << 4) + (rq << 2) + r;
        float v = acc[mf][nf][r] + bv2;
        if (res) v += h2f(res[(size_t)(m0 + ml) * 256 + n0 + nl]);
        if (relu) v = fmaxf(v, 0.f);
        epi[ml * 136 + nl] = f2h(v);
      }
  }
  __syncthreads();
  {
    int mr = tid >> 2, hf = (tid & 3) << 5;
    unsigned short* dst = hout + (size_t)(m0 + mr) * 256 + n0 + hf;
    const unsigned short* srow = epi + mr * 136 + hf;
#pragma unroll
    for (int k = 0; k < 4; ++k) *(uint4*)(dst + k * 8) = *(const uint4*)(srow + k * 8);
  }
  if (ut_next) {
    int nl = tid >> 2, sg2 = (tid & 3) << 5;
    unsigned short* dst = ut_next + ((size_t)(n0 + nl) * 256 + bc) * 128 + sg2;
#pragma unroll
    for (int k = 0; k < 4; ++k) {
      unsigned short v8[8];
#pragma unroll
      for (int e = 0; e < 8; ++e) v8[e] = epi[(sg2 + k * 8 + e) * 136 + nl];
      *(uint4*)(dst + k * 8) = *(uint4*)v8;
    }
  }
}

// ---------------- the whole network in one persistent kernel ----------------
__global__ __launch_bounds__(512, 4) void fused_net(
    const float* __restrict__ x, const float* __restrict__ wemb,
    const float* __restrict__ bemb,
    const float* __restrict__ log_dt, const float* __restrict__ logAre,
    const float* __restrict__ Aim, const float* __restrict__ Cre,
    const float* __restrict__ Cim, const float* __restrict__ dskip,
    const float* __restrict__ Wout, const float* __restrict__ bout,
    const float* __restrict__ gamma_, const float* __restrict__ beta_,
    const float* __restrict__ fb1, const float* __restrict__ fb2,
    const float* __restrict__ fcW, const float* __restrict__ fcb,
    const float* __restrict__ fW1, const float* __restrict__ fW2,
    float* __restrict__ WB, float* __restrict__ C2B, float* __restrict__ WLB,
    unsigned short* __restrict__ H, unsigned short* __restrict__ R,
    unsigned short* __restrict__ UT, unsigned short* __restrict__ GT,
    unsigned short* __restrict__ WT, float* __restrict__ part,
    float* __restrict__ outp, int* cnt) {
  __shared__ __align__(16) unsigned char LDSRAW[73728];
  int bid = blockIdx.x;
  int tid = threadIdx.x;
  int ep = 0;

  // ================= P0: precompute + wprep + embed =================
  if (bid < 192) {
    int idx = bid * 512 + tid;   // 192*512 = 98304 = NBLK*D*N exactly
    int blk = idx >> 14;
    int rem = idx & 16383;
    int d = rem >> 6;
    int n = rem & 63;
    float dt   = expf(log_dt[blk * D_ + d]);
    float are  = -expf(logAre[idx]);
    float aim  = Aim[idx];
    float dtar = dt * are, dtai = dt * aim;
    float er = expf(dtar);
    float wr = er * cosf(dtai);
    float wi = er * sinf(dtai);
    float inv = 1.0f / (are * are + aim * aim);
    float wm1r = wr - 1.0f;
    float br = (wm1r * are + wi * aim) * inv;
    float bi2 = (wi * are - wm1r * aim) * inv;
    float crv = Cre[idx], civ = Cim[idx];
    float c2r = 2.0f * (crv * br - civ * bi2);
    float c2i = 2.0f * (crv * bi2 + civ * br);
    float eL = expf((float)LC_ * dtar);
    float angL = (float)LC_ * dtai;
    float* wb = WB + (size_t)((blk << 8) + d) * 128;
    wb[n] = wr; wb[64 + n] = wi;
    float* cb = C2B + (size_t)((blk << 8) + d) * 128;
    cb[n] = c2r; cb[64 + n] = c2i;
    WLB[2 * idx] = eL * cosf(angL); WLB[2 * idx + 1] = eL * sinf(angL);
  } else if (bid < 320) {
    // wprep: task = bid-192 in 0..127 : wv(8) x tk(4) x tn(4)
    float (*tile)[65] = (float (*)[65])LDSRAW;
    int b2 = bid - 192;
    int wv = b2 >> 4, tk = (b2 >> 2) & 3, tn = b2 & 3;
    const float* src = (wv < 6) ? (Wout + (size_t)wv * 65536) : (wv == 6 ? fW1 : fW2);
    int r = tid >> 3, c = (tid & 7) << 3;
    float4 v0 = *(const float4*)(src + (size_t)(tk * 64 + r) * 256 + tn * 64 + c);
    float4 v1 = *(const float4*)(src + (size_t)(tk * 64 + r) * 256 + tn * 64 + c + 4);
    tile[r][c] = v0.x; tile[r][c + 1] = v0.y; tile[r][c + 2] = v0.z; tile[r][c + 3] = v0.w;
    tile[r][c + 4] = v1.x; tile[r][c + 5] = v1.y; tile[r][c + 6] = v1.z; tile[r][c + 7] = v1.w;
    __syncthreads();
    int n = tid >> 3, cc = (tid & 7) << 3;
    unsigned short o8[8];
#pragma unroll
    for (int e = 0; e < 8; ++e) o8[e] = f2h(tile[cc + e][n]);
    *(uint4*)(WT + (size_t)wv * 65536 + (size_t)(tn * 64 + n) * 256 + tk * 64 + cc) = *(uint4*)o8;
  }
  __syncthreads();
  {
    // embed: every block does one (bc, tau-half): bc = bid>>1, th = bid&1
    unsigned short* lds = (unsigned short*)LDSRAW;   // [256][72]
    int bc = bid >> 1, th = bid & 1;
    int b = bc >> 4, ch = bc & 15;
    int dl = (tid & 63) << 2;
    int tg = tid >> 6;
    float w4[4], b4[4];
#pragma unroll
    for (int i = 0; i < 4; ++i) { w4[i] = wemb[dl + i]; b4[i] = bemb[dl + i]; }
    for (int tt = 0; tt < 64; tt += 8) {
      int tau = tt + tg;
      int l = ch * 128 + th * 64 + tau;
      float xv = x[b * L_ + l];
      ushort4 hv;
      hv.x = f2h(fmaf(xv, w4[0], b4[0]));
      hv.y = f2h(fmaf(xv, w4[1], b4[1]));
      hv.z = f2h(fmaf(xv, w4[2], b4[2]));
      hv.w = f2h(fmaf(xv, w4[3], b4[3]));
      lds[(dl + 0) * 72 + tau] = hv.x;
      lds[(dl + 1) * 72 + tau] = hv.y;
      lds[(dl + 2) * 72 + tau] = hv.z;
      lds[(dl + 3) * 72 + tau] = hv.w;
      *(ushort4*)(H + ((size_t)(b * L_ + l)) * D_ + dl) = hv;
    }
    __syncthreads();
    int d = tid >> 1, sg = (tid & 1) << 5;
    unsigned short* dst = UT + ((size_t)d * 256 + bc) * 128 + th * 64 + sg;
    const unsigned short* srow = lds + d * 72 + sg;
    *(uint4*)(dst + 0)  = *(const uint4*)(srow + 0);
    *(uint4*)(dst + 8)  = *(const uint4*)(srow + 8);
    *(uint4*)(dst + 16) = *(const uint4*)(srow + 16);
    *(uint4*)(dst + 24) = *(const uint4*)(srow + 24);
  }
  gbar(cnt, (++ep) * NBLOCKS);

  // ================= 6 layers: scan -> bar -> gemm -> bar =================
#pragma unroll 1
  for (int blk = 0; blk < NBLK_; ++blk) {
    {
      // ---- scan (round-5 verified body): block = (d, batch-half) ----
      unsigned short* SLl = (unsigned short*)LDSRAW;            // [128][136]
      unsigned short* Bm  = SLl + 17408;                        // [128][136]
      float* wc = (float*)(LDSRAW + 69632);                     // [256]
      float* Kt = wc + 256;                                     // [128]
      float* Pb = Kt + 128;                                     // [128]
      float* Sb = Pb + 128;                                     // [128]
      int d = bid >> 1;
      int hm = (bid & 1) << 7;
      int lane = tid & 63, w = tid >> 6;
      int wm = w << 4;
      int cn = lane & 15, rq = lane >> 4;
      int ko = rq << 3;
      const unsigned short* Au = UT + ((size_t)d * 256 + hm) * 128;
      half8 afr[4];
#pragma unroll
      for (int kc2 = 0; kc2 < 4; ++kc2)
        afr[kc2] = *(const half8*)(Au + (size_t)(wm + cn) * 128 + (kc2 << 5) + ko);
      if (tid < 128) wc[tid] = WB[(size_t)((blk << 8) + d) * 128 + tid];
      else if (tid < 256) wc[tid] = C2B[(size_t)((blk << 8) + d) * 128 + (tid - 128)];
      __syncthreads();
      int n = tid & 63;
      float gd = gamma_[blk * D_ + d], bd = beta_[blk * D_ + d], dsk = dskip[blk * D_ + d];
      float wr = wc[n], wi = wc[64 + n];
      float c2r = wc[128 + n], c2i = wc[192 + n];
      float pr0, pi0;
      int j0 = w << 4;
      {
        float pr = 1.f, pi = 0.f, br = wr, bi = wi;
        int e = j0;
        while (e) {
          if (e & 1) { float tt = pr * br - pi * bi; pi = pr * bi + pi * br; pr = tt; }
          float t2 = br * br - bi * bi; bi = 2.f * br * bi; br = t2;
          e >>= 1;
        }
        pr0 = pr; pi0 = pi;
#pragma unroll 4
        for (int k2 = 0; k2 < 16; ++k2) {
          int j = j0 + k2;
          Bm[n * 136 + (127 - j)]        = f2h(gd * pr);
          Bm[(64 + n) * 136 + (127 - j)] = f2h(-gd * pi);
          float qr = pr * wr - pi * wi, qi = pr * wi + pi * wr;
          float kc = c2r * pr - c2i * pi;
#pragma unroll
          for (int off = 1; off < 64; off <<= 1) kc += __shfl_xor(kc, off);
          if (n == 0) Kt[j] = kc + (j == 0 ? dsk : 0.f);
          pr = qr; pi = qi;
        }
      }
      if (tid < 64) {
        const float* wlp = WLB + (((size_t)((blk << 8) + d)) * 64 + tid) * 2;
        float wlr = wlp[0], wli = wlp[1];
        float nr = wlr - 1.f, ni = wli;
        float dr2 = wc[tid] - 1.f, di = wc[64 + tid];
        float iv = 1.f / (dr2 * dr2 + di * di);
        Sb[tid]      = bd * ((nr * dr2 + ni * di) * iv);
        Sb[64 + tid] = bd * (-((ni * dr2 - nr * di) * iv));
      }
      __syncthreads();
      {
        f32x4 acc[8];
#pragma unroll
        for (int a = 0; a < 8; ++a) acc[a] = (f32x4){0.f, 0.f, 0.f, 0.f};
        __builtin_amdgcn_s_setprio(1);
#pragma unroll
        for (int kc = 0; kc < 4; ++kc) {
#pragma unroll
          for (int nf = 0; nf < 8; ++nf) {
            half8 bf = *(const half8*)((const _Float16*)Bm + ((nf << 4) + cn) * 136 + (kc << 5) + ko);
            acc[nf] = __builtin_amdgcn_mfma_f32_16x16x32_f16(afr[kc], bf, acc[nf], 0, 0, 0);
          }
        }
        __builtin_amdgcn_s_setprio(0);
#pragma unroll
        for (int nf = 0; nf < 8; ++nf) {
          int nl = (nf << 4) + cn;
          float sb = Sb[nl];
#pragma unroll
          for (int rr = 0; rr < 4; ++rr) {
            int row = wm + (rq << 2) + rr;
            SLl[row * 136 + nl] = f2h(acc[nf][rr] + sb);
          }
        }
      }
      __syncthreads();
      {
        float pr = pr0, pi = pi0;
#pragma unroll 4
        for (int k2 = 0; k2 < 16; ++k2) {
          int j = j0 + k2;
          float qr = pr * wr - pi * wi, qi = pr * wi + pi * wr;
          Bm[j * 136 + n]      = f2h(c2r * qr - c2i * qi);
          Bm[j * 136 + 64 + n] = f2h(c2r * qi + c2i * qr);
          pr = qr; pi = qi;
        }
      }
      if (tid < 128) {
        float ps = 0.f;
        for (int t2 = 0; t2 <= tid; ++t2) ps += Kt[t2];
        Pb[tid] = bd * ps;
      }
      {
        int b = tid >> 6, nn = tid & 63;
        const float* wlp = WLB + (((size_t)((blk << 8) + d)) * 64 + nn) * 2;
        float wlr = wlp[0], wli = wlp[1];
        float Sr = 0.f, Sj = 0.f;
        int row0 = b << 4;
        float tr2 = h2f(SLl[row0 * 136 + nn]);
        float tj2 = h2f(SLl[row0 * 136 + 64 + nn]);
        for (int c = 0; c < NC_; ++c) {
          int row = row0 + c;
          float ntr = 0.f, ntj = 0.f;
          if (c < NC_ - 1) {
            ntr = h2f(SLl[(row + 1) * 136 + nn]);
            ntj = h2f(SLl[(row + 1) * 136 + 64 + nn]);
          }
          SLl[row * 136 + nn]      = f2h(Sr);
          SLl[row * 136 + 64 + nn] = f2h(Sj);
          float nSr = fmaf(wlr, Sr, fmaf(wli, Sj, tr2));
          Sj = fmaf(-wli, Sr, fmaf(wlr, Sj, tj2));
          Sr = nSr;
          tr2 = ntr; tj2 = ntj;
        }
      }
      __syncthreads();
      f32x4 acc3[8];
#pragma unroll
      for (int a = 0; a < 8; ++a) acc3[a] = (f32x4){0.f, 0.f, 0.f, 0.f};
      __builtin_amdgcn_s_setprio(1);
#pragma unroll
      for (int kc2 = 0; kc2 < 4; ++kc2) {
        int kc = kc2 << 5;
        half8 af = *(const half8*)((const _Float16*)SLl + (wm + cn) * 136 + kc + ko);
#pragma unroll
        for (int nf = 0; nf < 8; ++nf) {
          half8 bf = *(const half8*)((const _Float16*)Bm + ((nf << 4) + cn) * 136 + kc + ko);
          acc3[nf] = __builtin_amdgcn_mfma_f32_16x16x32_f16(af, bf, acc3[nf], 0, 0, 0);
        }
      }
      __builtin_amdgcn_s_setprio(0);
      __syncthreads();
      {
        int chunk = tid & 15, rg = tid >> 4;
#pragma unroll
        for (int it = 0; it < 4; ++it) {
          int trow = (it << 5) + rg;
          int tau0 = chunk << 3;
          unsigned short v[8];
#pragma unroll
          for (int i = 0; i < 8; ++i) {
            int tau = tau0 + i;
            v[i] = (tau <= trow) ? f2h(gd * Kt[trow - tau]) : (unsigned short)0;
          }
          *(uint4*)(Bm + (size_t)trow * 136 + tau0) = *(uint4*)v;
        }
      }
      __syncthreads();
      {
        __builtin_amdgcn_s_setprio(1);
#pragma unroll
        for (int kc2 = 0; kc2 < 4; ++kc2) {
#pragma unroll
          for (int nf = 0; nf < 8; ++nf) {
            half8 bf = *(const half8*)((const _Float16*)Bm + ((nf << 4) + cn) * 136 + (kc2 << 5) + ko);
            acc3[nf] = __builtin_amdgcn_mfma_f32_16x16x32_f16(afr[kc2], bf, acc3[nf], 0, 0, 0);
          }
        }
        __builtin_amdgcn_s_setprio(0);
#pragma unroll
        for (int nf = 0; nf < 8; ++nf) {
          int nl = (nf << 4) + cn;
          float pb2 = Pb[nl];
#pragma unroll
          for (int rr = 0; rr < 4; ++rr) {
            int ml = wm + (rq << 2) + rr;
            float xx = acc3[nf][rr] + pb2;
            float x3 = xx * xx * xx;
            float inner = 0.7978845608028654f * fmaf(0.044715f, x3, xx);
            float e = __expf(-2.f * fabsf(inner));
            float th = (1.f - e) / (1.f + e);
            th = copysignf(th, inner);
            SLl[ml * 136 + nl] = f2h(0.5f * xx * (1.f + th));
          }
        }
        __syncthreads();
        int mr = tid >> 2, hf = (tid & 3) << 5;
        size_t gb2 = ((size_t)d * 256 + hm + mr) * 128 + hf;
#pragma unroll
        for (int k = 0; k < 4; ++k)
          *(uint4*)(GT + gb2 + k * 8) = *(const uint4*)&SLl[mr * 136 + hf + k * 8];
      }
    }
    gbar(cnt, (++ep) * NBLOCKS);

    // ---- projection gemm ----
    {
      const unsigned short* hin = (blk == 4) ? R : H;
      unsigned short* hout = (blk == 3) ? R : H;
      gemm_phase(LDSRAW, bid, tid, GT, WT + (size_t)blk * 65536, bout + blk * D_,
                 hin, hout, (blk < 5) ? UT : nullptr, true, false);
    }
    gbar(cnt, (++ep) * NBLOCKS);
  }

  // ================= FFN (Gbf aliases GT) =================
  gemm_phase(LDSRAW, bid, tid, H, WT + (size_t)6 * 65536, fb1, nullptr, GT, nullptr, false, true);
  gbar(cnt, (++ep) * NBLOCKS);
  gemm_phase(LDSRAW, bid, tid, GT, WT + (size_t)7 * 65536, fb2, R, H, nullptr, false, true);
  gbar(cnt, (++ep) * NBLOCKS);

  // ================= head =================
  if (bid < 256) {
    float* hs = (float*)LDSRAW;   // [2][256]
    int b = bid >> 4, ls = bid & 15;
    int d = tid & 255, hh = tid >> 8;
    const unsigned short* p = H + ((size_t)(b * L_ + ls * 128 + hh * 64)) * D_ + d;
    float sum = 0.f;
    for (int l = 0; l < 64; ++l) sum += h2f(p[(size_t)l * D_]);
    hs[hh * 256 + d] = sum;
    __syncthreads();
    if (tid < 256) part[(b * 16 + ls) * D_ + tid] = hs[tid] + hs[256 + tid];
  }
  gbar(cnt, (++ep) * NBLOCKS);
  if (bid < 16) {
    float* mv = (float*)LDSRAW;
    int b = bid;
    if (tid < 256) {
      float s = 0.f;
      for (int i = 0; i < 16; ++i) s += part[(b * 16 + i) * D_ + tid];
      mv[tid] = s * (1.0f / (float)L_);
    }
    __syncthreads();
    if (tid < 2) {
      float accv = fcb[tid];
      for (int k = 0; k < D_; ++k) accv = fmaf(mv[k], fcW[k * 2 + tid], accv);
      outp[b * 2 + tid] = accv;
    }
  }
}

extern "C" void kernel_launch(void* const* d_in, const int* in_sizes, int n_in,
                              void* d_out, int out_size, void* d_ws, size_t ws_size,
                              hipStream_t stream) {
  const float* x      = (const float*)d_in[0];
  const float* W_emb  = (const float*)d_in[1];
  const float* b_emb  = (const float*)d_in[2];
  const float* log_dt = (const float*)d_in[3];
  const float* logAre = (const float*)d_in[4];
  const float* Aim    = (const float*)d_in[5];
  const float* Cre    = (const float*)d_in[6];
  const float* Cim    = (const float*)d_in[7];
  const float* Dskip  = (const float*)d_in[8];
  const float* Wout   = (const float*)d_in[9];
  const float* bout   = (const float*)d_in[10];
  const float* gamma_ = (const float*)d_in[11];
  const float* beta_  = (const float*)d_in[12];
  const float* fW1    = (const float*)d_in[13];
  const float* fb1    = (const float*)d_in[14];
  const float* fW2    = (const float*)d_in[15];
  const float* fb2    = (const float*)d_in[16];
  const float* fcW    = (const float*)d_in[17];
  const float* fcb    = (const float*)d_in[18];
  float* outp = (float*)d_out;

  const size_t HSZ = (size_t)B_ * L_ * D_;   // 8388608
  float* WB     = (float*)d_ws;                          // 196608 f
  float* C2B    = WB + (size_t)NBLK_ * D_ * 128;         // 196608 f
  float* WLB    = C2B + (size_t)NBLK_ * D_ * 128;        // 196608 f
  unsigned short* H   = (unsigned short*)(WLB + (size_t)NBLK_ * D_ * N_ * 2);
  unsigned short* R   = H + HSZ;
  unsigned short* UT  = R + HSZ;
  unsigned short* GT  = UT + HSZ;
  unsigned short* WT  = GT + HSZ;                        // 524288 us
  float* part = (float*)(WT + (size_t)8 * 65536);        // 65536 f
  int* ctrl = (int*)(part + 65536);                      // 1 int: cnt

  hipMemsetAsync(ctrl, 0, sizeof(int), stream);
  fused_net<<<NBLOCKS, 512, 0, stream>>>(
      x, W_emb, b_emb, log_dt, logAre, Aim, Cre, Cim, Dskip,
      Wout, bout, gamma_, beta_, fb1, fb2, fcW, fcb, fW1, fW2,
      WB, C2B, WLB, H, R, UT, GT, WT, part, outp, ctrl);
}